// Round 6
// baseline (215.185 us; speedup 1.0000x reference)
//
#include <hip/hip_runtime.h>
#include <math.h>

#define EPS 1e-05

static constexpr int BLOCK  = 256;
static constexpr int BPB    = 768;   // blocks per batch -> 3072 blocks total = 12/CU (8 resident, 100% occ)
static constexpr int KPT    = 9;     // float4s per thread per stream (768*256*9 = 192^3/4)
static constexpr int NBATCH = 4;
static constexpr long long NPB = 192LL * 192LL * 192LL; // 7,077,888 elems/batch

typedef float v4f __attribute__((ext_vector_type(4)));

__device__ __forceinline__ double wave_reduce(double v) {
    #pragma unroll
    for (int off = 32; off > 0; off >>= 1)
        v += __shfl_down(v, off, 64);
    return v;
}

__global__ __launch_bounds__(BLOCK) void ncc_partial(
    const float* __restrict__ y_pred, const float* __restrict__ y_true,
    double* __restrict__ part)
{
    const int b  = blockIdx.y;
    const int bx = blockIdx.x;
    const v4f* __restrict__ I4 = (const v4f*)(y_true + (long long)b * NPB);
    const v4f* __restrict__ J4 = (const v4f*)(y_pred + (long long)b * NPB);

    // 32-bit indexing: max float4 index 1,769,471 -> byte offset < 28.4 MB.
    // SAME index for both streams (pairing required for IJ_sum).
    const unsigned base = (unsigned)bx * (BLOCK * KPT) + threadIdx.x;

    double sI = 0.0, sJ = 0.0, sI2 = 0.0, sJ2 = 0.0, sIJ = 0.0;

    // 2-deep rotation: next pair's loads issue before current pair's math.
    // Non-temporal: streaming data, bypass cache allocation (216 MiB footprint
    // thrashes the 256 MiB L3 otherwise — nt was the R5 win, keep it).
    v4f a0 = __builtin_nontemporal_load(I4 + base);
    v4f c0 = __builtin_nontemporal_load(J4 + base);
    #pragma unroll
    for (int k = 0; k < KPT; ++k) {
        v4f a1, c1;
        if (k + 1 < KPT) {
            a1 = __builtin_nontemporal_load(I4 + base + (k + 1) * BLOCK);
            c1 = __builtin_nontemporal_load(J4 + base + (k + 1) * BLOCK);
        }
        // f32 per-group math (cc error ~1e-10 vs 4.1e-6 threshold), f64 accumulate.
        float gI  = (a0.x + a0.y) + (a0.z + a0.w);
        float gJ  = (c0.x + c0.y) + (c0.z + c0.w);
        float gI2 = fmaf(a0.x, a0.x, fmaf(a0.y, a0.y, fmaf(a0.z, a0.z, a0.w * a0.w)));
        float gJ2 = fmaf(c0.x, c0.x, fmaf(c0.y, c0.y, fmaf(c0.z, c0.z, c0.w * c0.w)));
        float gIJ = fmaf(a0.x, c0.x, fmaf(a0.y, c0.y, fmaf(a0.z, c0.z, a0.w * c0.w)));
        sI  += (double)gI;
        sJ  += (double)gJ;
        sI2 += (double)gI2;
        sJ2 += (double)gJ2;
        sIJ += (double)gIJ;
        a0 = a1;
        c0 = c1;
    }

    sI  = wave_reduce(sI);
    sJ  = wave_reduce(sJ);
    sI2 = wave_reduce(sI2);
    sJ2 = wave_reduce(sJ2);
    sIJ = wave_reduce(sIJ);

    __shared__ double lds[BLOCK / 64][5];
    const int wave = threadIdx.x >> 6;
    const int lane = threadIdx.x & 63;
    if (lane == 0) {
        lds[wave][0] = sI;  lds[wave][1] = sJ;
        lds[wave][2] = sI2; lds[wave][3] = sJ2;
        lds[wave][4] = sIJ;
    }
    __syncthreads();
    if (threadIdx.x == 0) {
        double* p = part + ((long long)b * BPB + bx) * 5;
        #pragma unroll
        for (int k = 0; k < 5; ++k)
            p[k] = ((lds[0][k] + lds[1][k]) + (lds[2][k] + lds[3][k]));
    }
}

__global__ __launch_bounds__(BLOCK) void ncc_final(
    const double* __restrict__ part, float* __restrict__ out)
{
    const int b = blockIdx.x;
    double s[5] = {0.0, 0.0, 0.0, 0.0, 0.0};
    #pragma unroll
    for (int i = 0; i < BPB / BLOCK; ++i) {
        const double* p = part + ((long long)b * BPB + i * BLOCK + threadIdx.x) * 5;
        #pragma unroll
        for (int k = 0; k < 5; ++k) s[k] += p[k];
    }
    #pragma unroll
    for (int k = 0; k < 5; ++k) s[k] = wave_reduce(s[k]);

    __shared__ double lds[BLOCK / 64][5];
    const int wave = threadIdx.x >> 6;
    const int lane = threadIdx.x & 63;
    if (lane == 0) {
        #pragma unroll
        for (int k = 0; k < 5; ++k) lds[wave][k] = s[k];
    }
    __syncthreads();
    if (threadIdx.x == 0) {
        double I_sum  = (lds[0][0] + lds[1][0]) + (lds[2][0] + lds[3][0]);
        double J_sum  = (lds[0][1] + lds[1][1]) + (lds[2][1] + lds[3][1]);
        double I2_sum = (lds[0][2] + lds[1][2]) + (lds[2][2] + lds[3][2]);
        double J2_sum = (lds[0][3] + lds[1][3]) + (lds[2][3] + lds[3][3]);
        double IJ_sum = (lds[0][4] + lds[1][4]) + (lds[2][4] + lds[3][4]);

        const double win = (double)NPB;
        const double u_I = I_sum / win;
        const double u_J = J_sum / win;
        const double cross = IJ_sum - u_J * I_sum - u_I * J_sum + u_I * u_J * win;
        const double I_var = I2_sum - 2.0 * u_I * I_sum + u_I * u_I * win;
        const double J_var = J2_sum - 2.0 * u_J * J_sum + u_J * u_J * win;
        const double cc = cross / (sqrt(I_var) * sqrt(J_var) + EPS);
        out[b] = (float)cc;
    }
}

extern "C" void kernel_launch(void* const* d_in, const int* in_sizes, int n_in,
                              void* d_out, int out_size, void* d_ws, size_t ws_size,
                              hipStream_t stream) {
    // setup_inputs order: y_pred, y_true. reference(y_pred, y_true): Ii=y_true, Ji=y_pred.
    const float* y_pred = (const float*)d_in[0];
    const float* y_true = (const float*)d_in[1];
    float* out = (float*)d_out;
    double* part = (double*)d_ws;   // 4 * 768 * 5 * 8 B = 120 KB

    dim3 grid1(BPB, NBATCH);
    ncc_partial<<<grid1, BLOCK, 0, stream>>>(y_pred, y_true, part);
    ncc_final<<<NBATCH, BLOCK, 0, stream>>>(part, out);
}